// Round 2
// baseline (1000.051 us; speedup 1.0000x reference)
//
#include <hip/hip_runtime.h>
#include <hip/hip_bf16.h>
#include <math.h>
#include <stdint.h>

#define NTOK 8192      // B*T = 4*2048
#define DM   1024
#define SK   512
#define KD   256
#define VD   512
#define TK   32

typedef float f32x4 __attribute__((ext_vector_type(4)));
typedef short s16x8 __attribute__((ext_vector_type(8)));

#define AS1 __attribute__((address_space(1)))
#define AS3 __attribute__((address_space(3)))

__device__ __forceinline__ ushort f2bf(float f) {
  union { float f; uint32_t u; } v; v.f = f;
  return (ushort)((v.u + 0x7fffu + ((v.u >> 16) & 1u)) >> 16);  // RNE
}

// ---------------- conversion / precompute kernels ----------------

// cast x, Wq, codebook_a, codebook_b to bf16 in one grid (all float4-granular)
__global__ void k_cast_pack(const float* __restrict__ x, const float* __restrict__ Wq,
                            const float* __restrict__ cba, const float* __restrict__ cbb,
                            ushort* __restrict__ xb, ushort* __restrict__ Wqb,
                            ushort* __restrict__ cbab, ushort* __restrict__ cbbb) {
  const int NX4 = NTOK * DM / 4, NW4 = DM * 512 / 4, NC4 = SK * KD / 4;
  int i = blockIdx.x * 256 + threadIdx.x;
  const float* src; ushort* dst;
  if (i < NX4) { src = x; dst = xb; }
  else if ((i -= NX4) < NW4) { src = Wq; dst = Wqb; }
  else if ((i -= NW4) < NC4) { src = cba; dst = cbab; }
  else if ((i -= NC4) < NC4) { src = cbb; dst = cbbb; }
  else return;
  float4 v = ((const float4*)src)[i];
  ushort4 o;
  o.x = f2bf(v.x); o.y = f2bf(v.y); o.z = f2bf(v.z); o.w = f2bf(v.w);
  ((ushort4*)dst)[i] = o;
}

// Wo [512][1024] -> WoT [1024][512] bf16
__global__ void k_woT(const float* __restrict__ Wo, ushort* __restrict__ WoT) {
  int t = blockIdx.x * 256 + threadIdx.x;   // 524288 threads
  int k = t >> 10, n = t & 1023;
  WoT[n * 512 + k] = f2bf(Wo[t]);
}

// cbias[n] = sum_c bq_half[c] * cb[n][c]
__global__ void k_cbias(const float* __restrict__ bq, const float* __restrict__ cba,
                        const float* __restrict__ cbb, float* __restrict__ cbias) {
  int n = blockIdx.x * 256 + threadIdx.x;
  if (n >= 1024) return;
  const float* cb = (n < SK) ? (cba + n * KD) : (cbb + (n - SK) * KD);
  const float* b  = (n < SK) ? bq : (bq + KD);
  float s = 0.f;
  for (int c = 0; c < KD; c++) s += b[c] * cb[c];
  cbias[n] = s;
}

// ---------------- bf16 MFMA GEMM:  C[M][N] = A[M][K] * BT[N][K]^T (+bias)(+resid) ----------------
// 128x128 tile, BK=32, 4 waves in 2x2, each wave 4x4 tiles of 16x16x32.
// If Cb != nullptr, output is written as bf16 to Cb instead of float to C.

__device__ __forceinline__ void gload_lds16(const ushort* g, ushort* l) {
  __builtin_amdgcn_global_load_lds((const AS1 uint32_t*)g, (AS3 uint32_t*)l, 16, 0, 0);
}

__global__ __launch_bounds__(256, 2) void k_gemm_bt(
    const ushort* __restrict__ A, int lda,
    const ushort* __restrict__ BT, int ldb,
    float* __restrict__ C, ushort* __restrict__ Cb, int ldc,
    const float* __restrict__ bias,
    const float* __restrict__ resid,
    int K) {
  __shared__ ushort smA[128 * 32];
  __shared__ ushort smB[128 * 32];
  const int tM = blockIdx.x, tN = blockIdx.y;
  const int wave = threadIdx.x >> 6, lane = threadIdx.x & 63;
  const int wm = wave >> 1, wn = wave & 1;

  f32x4 acc[4][4];
#pragma unroll
  for (int mt = 0; mt < 4; mt++)
#pragma unroll
    for (int nt = 0; nt < 4; nt++) acc[mt][nt] = (f32x4)0.f;

  // staging: each wave issues 2 A-loads + 2 B-loads of 1KB (16 rows x 64B)
  const int r0 = (wave * 2 + 0) * 16 + (lane >> 2);
  const int r1 = (wave * 2 + 1) * 16 + (lane >> 2);
  const int koff = (lane & 3) * 8;            // element offset within BK
  const ushort* Ab = A + (size_t)tM * 128 * lda;
  const ushort* Bb = BT + (size_t)tN * 128 * ldb;
  ushort* ldsA0 = smA + (wave * 2 + 0) * 512;  // 16 rows * 32 cols
  ushort* ldsA1 = smA + (wave * 2 + 1) * 512;
  ushort* ldsB0 = smB + (wave * 2 + 0) * 512;
  ushort* ldsB1 = smB + (wave * 2 + 1) * 512;

  for (int k0 = 0; k0 < K; k0 += 32) {
    gload_lds16(Ab + (size_t)r0 * lda + k0 + koff, ldsA0);
    gload_lds16(Ab + (size_t)r1 * lda + k0 + koff, ldsA1);
    gload_lds16(Bb + (size_t)r0 * ldb + k0 + koff, ldsB0);
    gload_lds16(Bb + (size_t)r1 * ldb + k0 + koff, ldsB1);
    __syncthreads();
#pragma unroll
    for (int kk = 0; kk < 32; kk += 16) {
      s16x8 af[4], bf[4];
      const int ak = kk + (lane >> 4) * 8;
      const int am = wm * 64 + (lane & 15);
      const int bn = wn * 64 + (lane & 15);
#pragma unroll
      for (int mt = 0; mt < 4; mt++) af[mt] = *(const s16x8*)(smA + (am + mt * 16) * 32 + ak);
#pragma unroll
      for (int nt = 0; nt < 4; nt++) bf[nt] = *(const s16x8*)(smB + (bn + nt * 16) * 32 + ak);
#pragma unroll
      for (int mt = 0; mt < 4; mt++)
#pragma unroll
        for (int nt = 0; nt < 4; nt++)
          acc[mt][nt] = __builtin_amdgcn_mfma_f32_16x16x32_bf16(af[mt], bf[nt], acc[mt][nt], 0, 0, 0);
    }
    __syncthreads();
  }

  // epilogue: C/D layout col=lane&15, row=(lane>>4)*4+r
#pragma unroll
  for (int nt = 0; nt < 4; nt++) {
    const int col = tN * 128 + wn * 64 + nt * 16 + (lane & 15);
    const float bv = bias ? bias[col] : 0.f;
#pragma unroll
    for (int mt = 0; mt < 4; mt++) {
      const int rowb = tM * 128 + wm * 64 + mt * 16 + ((lane >> 4) << 2);
#pragma unroll
      for (int r = 0; r < 4; r++) {
        const size_t off = (size_t)(rowb + r) * ldc + col;
        float vv = acc[mt][nt][r] + bv;
        if (resid) vv += resid[off];
        if (Cb) Cb[off] = f2bf(vv);
        else    C[off] = vv;
      }
    }
  }
}

// ---------------- topk + softmax + value gather (one wave per token) ----------------

__device__ __forceinline__ void argmax64(float& bv, int& bi) {
#pragma unroll
  for (int off = 32; off >= 1; off >>= 1) {
    float ov = __shfl_xor(bv, off);
    int oi = __shfl_xor(bi, off);
    if (ov > bv || (ov == bv && oi < bi)) { bv = ov; bi = oi; }
  }
}

__global__ __launch_bounds__(256) void k_topk_gather(
    const float* __restrict__ scores,   // [NTOK][1024]
    const float* __restrict__ values,   // [SK*SK][VD]
    ushort* __restrict__ outb) {        // [NTOK][VD] bf16
  __shared__ float sa[4][TK], sb[4][TK], fw[4][TK];
  __shared__ int ia[4][TK], ib[4][TK], fidx[4][TK];
  const int wave = threadIdx.x >> 6, lane = threadIdx.x & 63;
  const int tok = blockIdx.x * 4 + wave;
  const float* srow = scores + (size_t)tok * 1024;

  // phase A/B: top-32 of 512 scores for each half
  for (int h = 0; h < 2; h++) {
    const float* s = srow + h * 512;
    float v[8];
    float4 p0 = ((const float4*)s)[lane * 2];
    float4 p1 = ((const float4*)s)[lane * 2 + 1];
    v[0] = p0.x; v[1] = p0.y; v[2] = p0.z; v[3] = p0.w;
    v[4] = p1.x; v[5] = p1.y; v[6] = p1.z; v[7] = p1.w;
    float* SV = h ? sb[wave] : sa[wave];
    int*   SI = h ? ib[wave] : ia[wave];
    for (int r = 0; r < TK; r++) {
      float bv = v[0]; int bl = 0;
#pragma unroll
      for (int t = 1; t < 8; t++) if (v[t] > bv) { bv = v[t]; bl = t; }
      int bi = lane * 8 + bl;
      argmax64(bv, bi);
      if ((bi >> 3) == lane) {
        const int t0 = bi & 7;
#pragma unroll
        for (int t = 0; t < 8; t++) if (t == t0) v[t] = -INFINITY;
      }
      if (lane == 0) { SV[r] = bv; SI[r] = bi; }
    }
  }

  // phase C: top-32 of the 1024 pairwise sums; p = i*32+j with i=p>>5, j=p&31
  float cs[16];
#pragma unroll
  for (int t = 0; t < 16; t++) {
    const int p = t * 64 + lane;
    cs[t] = sa[wave][p >> 5] + sb[wave][p & 31];
  }
  for (int r = 0; r < TK; r++) {
    float bv = cs[0]; int bt = 0;
#pragma unroll
    for (int t = 1; t < 16; t++) if (cs[t] > bv) { bv = cs[t]; bt = t; }
    int gp = bt * 64 + lane;
    argmax64(bv, gp);
    const bool zap = (lane == (gp & 63));
    const int zt = gp >> 6;
#pragma unroll
    for (int t = 0; t < 16; t++) if (zap && t == zt) cs[t] = -INFINITY;
    if (lane == 0) {
      fw[wave][r] = bv;
      fidx[wave][r] = ia[wave][gp >> 5] * SK + ib[wave][gp & 31];
    }
  }

  // phase D: softmax over the 32 final scores (lanes 0..31)
  {
    float f = (lane < TK) ? fw[wave][lane] : -INFINITY;
    float m = f;
#pragma unroll
    for (int off = 16; off >= 1; off >>= 1) m = fmaxf(m, __shfl_xor(m, off));
    float e = (lane < TK) ? __expf(f - m) : 0.f;
    float ssum = e;
#pragma unroll
    for (int off = 16; off >= 1; off >>= 1) ssum += __shfl_xor(ssum, off);
    if (lane < TK) fw[wave][lane] = e / ssum;
  }

  // phase E: weighted gather of value rows -> out bf16
  float acc[8] = {0.f, 0.f, 0.f, 0.f, 0.f, 0.f, 0.f, 0.f};
  for (int r = 0; r < TK; r++) {
    const int idx = fidx[wave][r];
    const float wr = fw[wave][r];
    const float4* row = (const float4*)(values + (size_t)idx * VD);
    float4 a = row[lane * 2];
    float4 b = row[lane * 2 + 1];
    acc[0] += wr * a.x; acc[1] += wr * a.y; acc[2] += wr * a.z; acc[3] += wr * a.w;
    acc[4] += wr * b.x; acc[5] += wr * b.y; acc[6] += wr * b.z; acc[7] += wr * b.w;
  }
  uint4 st;
  st.x = (uint32_t)f2bf(acc[0]) | ((uint32_t)f2bf(acc[1]) << 16);
  st.y = (uint32_t)f2bf(acc[2]) | ((uint32_t)f2bf(acc[3]) << 16);
  st.z = (uint32_t)f2bf(acc[4]) | ((uint32_t)f2bf(acc[5]) << 16);
  st.w = (uint32_t)f2bf(acc[6]) | ((uint32_t)f2bf(acc[7]) << 16);
  *(uint4*)(outb + (size_t)tok * VD + lane * 8) = st;
}

// ---------------- LayerNorm (in place on d_out) ----------------

__global__ __launch_bounds__(256) void k_ln(const float* __restrict__ y,
                                            const float* __restrict__ gamma,
                                            const float* __restrict__ beta,
                                            float* __restrict__ out) {
  const int tok = blockIdx.x, t = threadIdx.x;
  __shared__ float red[8];
  float4 v = ((const float4*)(y + (size_t)tok * DM))[t];
  float s = v.x + v.y + v.z + v.w;
  float ss = v.x * v.x + v.y * v.y + v.z * v.z + v.w * v.w;
#pragma unroll
  for (int off = 32; off >= 1; off >>= 1) {
    s += __shfl_xor(s, off);
    ss += __shfl_xor(ss, off);
  }
  const int wave = t >> 6, lane = t & 63;
  if (lane == 0) { red[wave] = s; red[4 + wave] = ss; }
  __syncthreads();
  if (t == 0) {
    float S = red[0] + red[1] + red[2] + red[3];
    float SS = red[4] + red[5] + red[6] + red[7];
    float mu = S * (1.f / DM);
    float var = SS * (1.f / DM) - mu * mu;
    red[0] = mu;
    red[1] = rsqrtf(var + 1e-5f);
  }
  __syncthreads();
  const float mu = red[0], rs = red[1];
  float4 g = ((const float4*)gamma)[t];
  float4 b = ((const float4*)beta)[t];
  float4 o;
  o.x = (v.x - mu) * rs * g.x + b.x;
  o.y = (v.y - mu) * rs * g.y + b.y;
  o.z = (v.z - mu) * rs * g.z + b.z;
  o.w = (v.w - mu) * rs * g.w + b.w;
  ((float4*)(out + (size_t)tok * DM))[t] = o;
}

// ---------------- host launcher ----------------
// Workspace layout (25.0 MB total; scores lives in d_out, which is 32 MB):
//   [0,16M)        xb   : x in bf16          (live: cast -> scores GEMM)
//   [16M,24M)      U    : union region
//       U+0      Wqb  (1M)   \
//       U+1M     cbab (256K)  | live: cast -> scores GEMM
//       U+1.25M  cbbb (256K)  |
//       U+1.5M   MTb  (2M)   /
//       U+0      outb (8M)  aliases the above, live: topk -> GEMM2
//   [24M,25M)      WoTb (1M)  (live: start -> GEMM2)
//   [25M,25M+4K)   cbias

extern "C" void kernel_launch(void* const* d_in, const int* in_sizes, int n_in,
                              void* d_out, int out_size, void* d_ws, size_t ws_size,
                              hipStream_t stream) {
  (void)in_sizes; (void)n_in; (void)out_size; (void)ws_size;
  const float* x      = (const float*)d_in[0];
  const float* Wq     = (const float*)d_in[1];
  const float* bq     = (const float*)d_in[2];
  const float* cba    = (const float*)d_in[3];
  const float* cbb    = (const float*)d_in[4];
  const float* values = (const float*)d_in[5];
  const float* Wo     = (const float*)d_in[6];
  const float* bo     = (const float*)d_in[7];
  const float* gamma  = (const float*)d_in[8];
  const float* beta   = (const float*)d_in[9];
  float* out = (float*)d_out;

  char* ws = (char*)d_ws;
  const size_t MB = 1024 * 1024;
  ushort* xb    = (ushort*)(ws);                 // 16 MB
  char*   U     = ws + 16 * MB;
  ushort* Wqb   = (ushort*)(U);                  // 1 MB
  ushort* cbab  = (ushort*)(U + 1 * MB);         // 256 KB
  ushort* cbbb  = (ushort*)(U + 1 * MB + 256 * 1024); // 256 KB
  ushort* MTb   = (ushort*)(U + 3 * MB / 2);     // 2 MB
  ushort* outb  = (ushort*)(U);                  // 8 MB (aliases Wqb/cb/MTb, later)
  ushort* WoTb  = (ushort*)(ws + 24 * MB);       // 1 MB
  float*  cbias = (float*)(ws + 25 * MB);        // 4 KB
  float*  scores = out;                          // 32 MB, d_out as scratch

  // 1) casts + small precompute
  k_cast_pack<<<8960, 256, 0, stream>>>(x, Wq, cba, cbb, xb, Wqb, cbab, cbbb);
  k_woT<<<2048, 256, 0, stream>>>(Wo, WoTb);
  k_cbias<<<4, 256, 0, stream>>>(bq, cba, cbb, cbias);

  // 2) merged score matrix MT[n][d] (bf16 direct): n<512 from codebook_a x Wq[:, :256],
  //    n>=512 from codebook_b x Wq[:, 256:]
  k_gemm_bt<<<dim3(4, 8), 256, 0, stream>>>(cbab, KD, Wqb, 512, nullptr, MTb, 1024,
                                            nullptr, nullptr, KD);
  k_gemm_bt<<<dim3(4, 8), 256, 0, stream>>>(cbbb, KD, Wqb + KD, 512, nullptr, MTb + 512 * 1024, 1024,
                                            nullptr, nullptr, KD);

  // 3) scores[8192][1024] = x @ MT^T + cbias   (into d_out)
  k_gemm_bt<<<dim3(64, 8), 256, 0, stream>>>(xb, DM, MTb, 1024, scores, nullptr, 1024,
                                             cbias, nullptr, DM);

  // 4) topk + softmax + weighted value gather -> outb bf16 (clobbers Wqb/cb/MTb)
  k_topk_gather<<<2048, 256, 0, stream>>>(scores, values, outb);

  // 5) y = x + outb @ Wo + bo  (overwrites d_out)
  k_gemm_bt<<<dim3(64, 8), 256, 0, stream>>>(outb, VD, WoTb, VD, out, nullptr, 1024,
                                             bo, x, VD);

  // 6) LayerNorm in place
  k_ln<<<NTOK, 256, 0, stream>>>(out, gamma, beta, out);
}